// Round 10
// baseline (117.682 us; speedup 1.0000x reference)
//
#include <hip/hip_runtime.h>

#define NBATCH 2
#define NPTS   16384
#define TPTS   32                      // points per MFMA tile (32x32x16)
#define NTILES (NPTS / TPTS)           // 512
#define JCH    16                      // col-chunks per (dir,n): 1024 cols each
#define NT_PER (NTILES / JCH)          // 32 col-tiles per chunk
#define TG     (NTILES / 4)            // 128 tile-groups (4 row-tiles per block)

typedef float f32x16 __attribute__((ext_vector_type(16)));
typedef short s16x8 __attribute__((ext_vector_type(8)));

__device__ __forceinline__ unsigned short f2bf(float f) {   // RTNE, finite inputs
    unsigned u = __float_as_uint(f);
    u += 0x7FFF + ((u >> 16) & 1);
    return (unsigned short)(u >> 16);
}
__device__ __forceinline__ float bf2f(unsigned short h) {
    return __uint_as_float((unsigned)h << 16);
}
__device__ __forceinline__ unsigned umin2(unsigned a, unsigned b) { return a < b ? a : b; }

// K=16 panels for 32x32x16 bf16 MFMA — A-side AND B-side encodings for BOTH
// clouds (R9-proven payload).
// A slots: [ah(3) | al(3) | ah(3) | 1 1 | sqa_h sqa_l | 1 | 0 0]
// B slots: [-2bh(3)| -2bh(3)| -2bl(3)| sqb_h sqb_l | 1 1 | 1 | 0 0]
// dot = 1 + sqa + sqb - 2(ah+al)·bh - 2ah·bl = 1 + d^2 + err, |err| <~ 1e-4.
// (+1 bias keeps keys positive; exact rescue removes all approx error)
__global__ __launch_bounds__(256) void pack_panels(
    const float* __restrict__ c1, const float* __restrict__ c2,
    unsigned short* __restrict__ apan, unsigned short* __restrict__ bpan)
{
    int tid = blockIdx.x * 256 + threadIdx.x;   // 2^18 threads
    int lane = tid & 63;
    int tile = (tid >> 6) & (NTILES - 1);       // 9 bits
    int n    = (tid >> 15) & 1;
    int whichB = (tid >> 16) & 1;
    int wc     = (tid >> 17) & 1;               // which cloud

    const float* src = wc ? c2 : c1;

    int p = tile * TPTS + (lane & 31);
    const float* q = src + ((size_t)n * NPTS + p) * 3;
    float x = q[0], y = q[1], z = q[2];

    unsigned short xh = f2bf(x), yh = f2bf(y), zh = f2bf(z);
    unsigned short xl = f2bf(x - bf2f(xh)), yl = f2bf(y - bf2f(yh)), zl = f2bf(z - bf2f(zh));
    float sq = x * x + y * y + z * z;
    unsigned short sh = f2bf(sq);
    unsigned short sl = f2bf(sq - bf2f(sh));
    const unsigned short one = 0x3F80;

    unsigned short slots[16];
    if (!whichB) {
        slots[0]=xh;  slots[1]=yh;  slots[2]=zh;
        slots[3]=xl;  slots[4]=yl;  slots[5]=zl;
        slots[6]=xh;  slots[7]=yh;  slots[8]=zh;
        slots[9]=one; slots[10]=one;
        slots[11]=sh; slots[12]=sl;
        slots[13]=one; slots[14]=0; slots[15]=0;
    } else {
        unsigned short mxh=f2bf(-2.f*bf2f(xh)), myh=f2bf(-2.f*bf2f(yh)), mzh=f2bf(-2.f*bf2f(zh));
        unsigned short mxl=f2bf(-2.f*bf2f(xl)), myl=f2bf(-2.f*bf2f(yl)), mzl=f2bf(-2.f*bf2f(zl));
        slots[0]=mxh; slots[1]=myh; slots[2]=mzh;
        slots[3]=mxh; slots[4]=myh; slots[5]=mzh;
        slots[6]=mxl; slots[7]=myl; slots[8]=mzl;
        slots[9]=sh;  slots[10]=sl;
        slots[11]=one; slots[12]=one;
        slots[13]=one; slots[14]=0; slots[15]=0;
    }

    int j0 = (lane >> 5) * 8;
    uint4 w;
    w.x = (unsigned)slots[j0+0] | ((unsigned)slots[j0+1] << 16);
    w.y = (unsigned)slots[j0+2] | ((unsigned)slots[j0+3] << 16);
    w.z = (unsigned)slots[j0+4] | ((unsigned)slots[j0+5] << 16);
    w.w = (unsigned)slots[j0+6] | ((unsigned)slots[j0+7] << 16);
    unsigned short* pan = whichB ? bpan : apan;
    uint4* dst = (uint4*)pan + ((size_t)((wc * 2 + n) * NTILES + tile) * 64 + lane);
    *dst = w;
}

// Both chamfer directions as pure ROW-min folds (dir in the grid; dir1 uses
// the transposed product). Per 2 tiles per reg: 2 v_and_or_b32 + 1 v_min3_u32.
// No LDS, no shfl, no branches in the hot loop. Exact rescue at the end
// (R7/R9-proven: decode argmin, recompute d^2 in fp32 -> absmax 0).
// D layout (m74/m101, R7-HW-verified): col=lane&31, row=(r&3)+8*(r>>2)+4*(lane>>5).
__global__ __launch_bounds__(256, 4) void chamfer_rows(
    const float* __restrict__ c1, const float* __restrict__ c2,
    const unsigned short* __restrict__ apan, const unsigned short* __restrict__ bpan,
    unsigned int* __restrict__ mins /* [2][NBATCH][NPTS] */)
{
    int bid = blockIdx.x;
    const int jc  = bid & (JCH - 1); bid >>= 4;
    const int tg  = bid & (TG - 1);  bid >>= 7;
    const int n   = bid & 1;         bid >>= 1;
    const int dir = bid;             // 0: rows=c1, cols=c2 ; 1: rows=c2, cols=c1

    const int lane   = threadIdx.x & 63;
    const int wv     = threadIdx.x >> 6;
    const int colw   = lane & 31;
    const int laneHi = lane >> 5;
    const int mt     = tg * 4 + wv;      // this wave's row-tile (32 rows)

    const s16x8 a = *(const s16x8*)(
        apan + ((size_t)((dir * 2 + n) * NTILES + mt) * 64 + lane) * 8);
    const unsigned short* Bbase =
        bpan + ((size_t)(((1 - dir) * 2 + n) * NTILES + jc * NT_PER) * 64 + lane) * 8;

    unsigned kk[16];
    #pragma unroll
    for (int r = 0; r < 16; ++r) kk[r] = 0xFFFFFFFFu;

    f32x16 cz = {0.f,0.f,0.f,0.f,0.f,0.f,0.f,0.f,0.f,0.f,0.f,0.f,0.f,0.f,0.f,0.f};

    unsigned v0 = (unsigned)colw;        // t*32 + colw
    unsigned v1 = (unsigned)colw + 32;

    for (int t = 0; t < NT_PER; t += 2) {
        s16x8 b0 = *(const s16x8*)(Bbase + (size_t)t * 512);
        s16x8 b1 = *(const s16x8*)(Bbase + (size_t)(t + 1) * 512);
        f32x16 d0 = __builtin_amdgcn_mfma_f32_32x32x16_bf16(a, b0, cz, 0, 0, 0);
        f32x16 d1 = __builtin_amdgcn_mfma_f32_32x32x16_bf16(a, b1, cz, 0, 0, 0);
        #pragma unroll
        for (int r = 0; r < 16; ++r) {
            unsigned t0 = (__float_as_uint(d0[r]) & 0xFFFFFC00u) | v0;   // v_and_or_b32
            unsigned t1 = (__float_as_uint(d1[r]) & 0xFFFFFC00u) | v1;
            asm("v_min3_u32 %0, %1, %2, %3"
                : "=v"(kk[r]) : "v"(kk[r]), "v"(t0), "v"(t1));
        }
        v0 += 64; v1 += 64;
    }

    // key-min across the 32 cols (lane bits 0-4), then ONE exact rescue/row.
    const float* ca = (dir ? c2 : c1) + (size_t)n * NPTS * 3;
    const float* cb = (dir ? c1 : c2) + (size_t)n * NPTS * 3;
    unsigned int* md = mins + (size_t)(dir * NBATCH + n) * NPTS;

    #pragma unroll
    for (int r = 0; r < 16; ++r) {
        unsigned k = kk[r];
        k = umin2(k, (unsigned)__shfl_xor((int)k, 1, 64));
        k = umin2(k, (unsigned)__shfl_xor((int)k, 2, 64));
        k = umin2(k, (unsigned)__shfl_xor((int)k, 4, 64));
        k = umin2(k, (unsigned)__shfl_xor((int)k, 8, 64));
        k = umin2(k, (unsigned)__shfl_xor((int)k, 16, 64));
        if (colw == 0) {
            int colg = jc * (NT_PER * TPTS) + (int)(k & 1023u);
            int rowg = mt * 32 + (r & 3) + 8 * (r >> 2) + 4 * laneHi;
            float dx = ca[rowg * 3 + 0] - cb[colg * 3 + 0];
            float dy = ca[rowg * 3 + 1] - cb[colg * 3 + 1];
            float dz = ca[rowg * 3 + 2] - cb[colg * 3 + 2];
            float d2 = fmaf(dx, dx, fmaf(dy, dy, dz * dz));   // exact fp32
            atomicMin(&md[rowg], __float_as_uint(d2));
        }
    }
}

// out[n] = mean_i min_a2b + mean_j min_b2a  (P1 == P2 so one divide).
__global__ __launch_bounds__(256) void chamfer_out(
    const unsigned int* __restrict__ mins, float* __restrict__ out)
{
    int n = blockIdx.x;
    float acc = 0.0f;
    for (int i = threadIdx.x; i < NPTS; i += 256) {
        acc += __uint_as_float(mins[(0 * NBATCH + n) * NPTS + i]);
        acc += __uint_as_float(mins[(1 * NBATCH + n) * NPTS + i]);
    }
    for (int off = 32; off > 0; off >>= 1) acc += __shfl_down(acc, off, 64);
    __shared__ float sm[4];
    int wv = threadIdx.x >> 6, ln = threadIdx.x & 63;
    if (ln == 0) sm[wv] = acc;
    __syncthreads();
    if (threadIdx.x == 0)
        out[n] = (sm[0] + sm[1] + sm[2] + sm[3]) / (float)NPTS;
}

extern "C" void kernel_launch(void* const* d_in, const int* in_sizes, int n_in,
                              void* d_out, int out_size, void* d_ws, size_t ws_size,
                              hipStream_t stream)
{
    const float* c1 = (const float*)d_in[0];
    const float* c2 = (const float*)d_in[1];
    float* out = (float*)d_out;

    char* ws = (char*)d_ws;
    // mins at base: 256 KiB. apan: 2 MiB (both clouds). bpan: 2 MiB.
    // Total 4.4375 MiB == R7-proven footprint.
    unsigned int*   mins = (unsigned int*)ws;
    unsigned short* apan = (unsigned short*)(ws + (size_t)(2 * NBATCH * NPTS) * 4);
    unsigned short* bpan = apan + (size_t)2 * NBATCH * NTILES * 512;

    hipMemsetAsync(mins, 0x7F, (size_t)2 * NBATCH * NPTS * sizeof(unsigned int), stream);

    pack_panels<<<(1 << 18) / 256, 256, 0, stream>>>(c1, c2, apan, bpan);
    chamfer_rows<<<2 * NBATCH * TG * JCH, 256, 0, stream>>>(c1, c2, apan, bpan, mins);
    chamfer_out<<<NBATCH, 256, 0, stream>>>(mins, out);
}

// Round 11
// 64.209 us; speedup vs baseline: 1.8328x; 1.8328x over previous
//
#include <hip/hip_runtime.h>

#define NBATCH 2
#define NPTS   16384
#define TPTS   32                      // points per MFMA tile (32x32x16)
#define NTILES (NPTS / TPTS)           // 512
#define JCH    16                      // col-chunks per batch: 1024 cols each
#define NT_PER (NTILES / JCH)          // 32 col-tiles per chunk
#define TG     (NTILES / 4)            // 128 row-groups (block = 4 waves = 128 rows)

typedef float f32x16 __attribute__((ext_vector_type(16)));
typedef short s16x8  __attribute__((ext_vector_type(8)));

__device__ __forceinline__ unsigned short f2bf(float f) {   // RTNE, finite inputs
    unsigned u = __float_as_uint(f);
    u += 0x7FFF + ((u >> 16) & 1);
    return (unsigned short)(u >> 16);
}
__device__ __forceinline__ float bf2f(unsigned short h) {
    return __uint_as_float((unsigned)h << 16);
}
__device__ __forceinline__ unsigned umin2(unsigned a, unsigned b) { return a < b ? a : b; }

// Inline-asm MFMA: VGPR destination (no ACC class -> no v_accvgpr_read tax),
// literal-0 C (no tied-C copy). Early-clobber dst so it can't alias a/b.
__device__ __forceinline__ f32x16 mfma32(s16x8 a, s16x8 b) {
    f32x16 d;
    asm volatile("v_mfma_f32_32x32x16_bf16 %0, %1, %2, 0"
                 : "=&v"(d) : "v"(a), "v"(b));
    return d;
}
__device__ __forceinline__ void min3f(float& acc, float x, float y) {
    asm("v_min3_f32 %0, %1, %2, %3" : "=v"(acc) : "v"(acc), "v"(x), "v"(y));
}
__device__ __forceinline__ float tree16(const f32x16& d) {  // min over 16 regs
    float c;
    asm("v_min3_f32 %0, %1, %2, %3" : "=v"(c) : "v"(d[0]), "v"(d[1]), "v"(d[2]));
    min3f(c, d[3],  d[4]);  min3f(c, d[5],  d[6]);
    min3f(c, d[7],  d[8]);  min3f(c, d[9],  d[10]);
    min3f(c, d[11], d[12]); min3f(c, d[13], d[14]);
    return fminf(c, d[15]);
}

// K=16 panels, ONE matrix: rows = cloud1 (A-side), cols = cloud2 (B-side).
// A slots: [ah(3) | al(3) | ah(3) | 1 1 | sqa_h sqa_l | 0 0 0]
// B slots: [-2bh(3)| -2bh(3)| -2bl(3)| sqb_h sqb_l | 1 1 | 0 0 0]
// dot = sqa + sqb - 2(ah+al)·bh - 2ah·bl = d^2 + eps, |eps| <~ 1.3e-4 worst.
// Also initializes the mins arrays (fused memset).
__global__ __launch_bounds__(256) void pack_panels(
    const float* __restrict__ c1, const float* __restrict__ c2,
    unsigned short* __restrict__ apan, unsigned short* __restrict__ bpan,
    unsigned int* __restrict__ mins)
{
    int tid = blockIdx.x * 256 + threadIdx.x;   // 2^17 threads
    if (tid < 2 * NBATCH * NPTS) mins[tid] = 0x7F7F7F7Fu;   // fused init

    int lane   = tid & 63;
    int tile   = (tid >> 6) & (NTILES - 1);
    int n      = (tid >> 15) & 1;
    int whichB = (tid >> 16) & 1;

    const float* src = whichB ? c2 : c1;

    int p = tile * TPTS + (lane & 31);
    const float* q = src + ((size_t)n * NPTS + p) * 3;
    float x = q[0], y = q[1], z = q[2];

    unsigned short xh = f2bf(x), yh = f2bf(y), zh = f2bf(z);
    unsigned short xl = f2bf(x - bf2f(xh)), yl = f2bf(y - bf2f(yh)), zl = f2bf(z - bf2f(zh));
    float sq = x * x + y * y + z * z;
    unsigned short sh = f2bf(sq);
    unsigned short sl = f2bf(sq - bf2f(sh));
    const unsigned short one = 0x3F80;

    unsigned short slots[16];
    if (!whichB) {
        slots[0]=xh;  slots[1]=yh;  slots[2]=zh;
        slots[3]=xl;  slots[4]=yl;  slots[5]=zl;
        slots[6]=xh;  slots[7]=yh;  slots[8]=zh;
        slots[9]=one; slots[10]=one;
        slots[11]=sh; slots[12]=sl;
        slots[13]=0;  slots[14]=0;  slots[15]=0;
    } else {
        unsigned short mxh=f2bf(-2.f*bf2f(xh)), myh=f2bf(-2.f*bf2f(yh)), mzh=f2bf(-2.f*bf2f(zh));
        unsigned short mxl=f2bf(-2.f*bf2f(xl)), myl=f2bf(-2.f*bf2f(yl)), mzl=f2bf(-2.f*bf2f(zl));
        slots[0]=mxh; slots[1]=myh; slots[2]=mzh;
        slots[3]=mxh; slots[4]=myh; slots[5]=mzh;
        slots[6]=mxl; slots[7]=myl; slots[8]=mzl;
        slots[9]=sh;  slots[10]=sl;
        slots[11]=one; slots[12]=one;
        slots[13]=0;  slots[14]=0;  slots[15]=0;
    }

    int j0 = (lane >> 5) * 8;
    uint4 w;
    w.x = (unsigned)slots[j0+0] | ((unsigned)slots[j0+1] << 16);
    w.y = (unsigned)slots[j0+2] | ((unsigned)slots[j0+3] << 16);
    w.z = (unsigned)slots[j0+4] | ((unsigned)slots[j0+5] << 16);
    w.w = (unsigned)slots[j0+6] | ((unsigned)slots[j0+7] << 16);
    unsigned short* pan = whichB ? bpan : apan;
    uint4* dst = (uint4*)pan + ((size_t)(n * NTILES + tile) * 64 + lane);
    *dst = w;
}

// One pass over the d^2 matrix -> BOTH reductions, raw-value min3 folds.
// 3-stage pipeline: load duo t+2 | MFMA duo t+1 | fold duo t. The s_nop asm
// is data-tied to the folded tuples so folds can't be scheduled into the
// MFMA hazard window. Col partials: per-wave LDS slices, plain stores
// (R9-proven), merged after syncthreads.
// D layout (R7/R9 HW-verified): col=lane&31, row=(r&3)+8*(r>>2)+4*(lane>>5).
__global__ __launch_bounds__(256, 4) void chamfer_mm(
    const unsigned short* __restrict__ apan, const unsigned short* __restrict__ bpan,
    unsigned int* __restrict__ rowmins, unsigned int* __restrict__ colmins)
{
    __shared__ unsigned int ldscol[4][NT_PER * TPTS];   // 16 KiB

    int bid = blockIdx.x;
    const int jc = bid & (JCH - 1); bid >>= 4;
    const int tg = bid & (TG - 1);  bid >>= 7;
    const int n  = bid;

    const int lane   = threadIdx.x & 63;
    const int wv     = threadIdx.x >> 6;
    const int colw   = lane & 31;
    const int laneHi = lane >> 5;
    const int mt     = tg * 4 + wv;      // this wave's row-tile (32 rows)

    const s16x8 a = *(const s16x8*)(
        apan + ((size_t)(n * NTILES + mt) * 64 + lane) * 8);
    const unsigned short* B =
        bpan + ((size_t)(n * NTILES + jc * NT_PER) * 64 + lane) * 8;

#define LDT(t) (*(const s16x8*)(B + (size_t)(t) * 512))

    float rmin[16];
    #pragma unroll
    for (int r = 0; r < 16; ++r) rmin[r] = 3.0e38f;

    // prologue: duos 0,1 loaded; duo0 in flight
    s16x8 bA0 = LDT(0), bA1 = LDT(1);
    s16x8 bB0 = LDT(2), bB1 = LDT(3);
    f32x16 dA0 = mfma32(a, bA0), dA1 = mfma32(a, bA1);
    f32x16 dB0, dB1;

    for (int j = 0; j < 16; j += 2) {
        {   // fold duo j (dA) | mfma duo j+1 (bB->dB) | load duo j+2 (->bA)
            int tl = ((j + 2) & 15) * 2;
            bA0 = LDT(tl); bA1 = LDT(tl + 1);
            dB0 = mfma32(a, bB0); dB1 = mfma32(a, bB1);
            __builtin_amdgcn_sched_barrier(0);
            asm volatile("s_nop 7\n\ts_nop 7" : "+v"(dA0), "+v"(dA1));
            const int t = j * 2;
            float c0 = tree16(dA0), c1 = tree16(dA1);
            c0 = fminf(c0, __shfl_xor(c0, 32, 64));
            c1 = fminf(c1, __shfl_xor(c1, 32, 64));
            ldscol[wv][t * 32 + colw]       = __float_as_uint(fmaxf(c0, 0.f));
            ldscol[wv][(t + 1) * 32 + colw] = __float_as_uint(fmaxf(c1, 0.f));
            #pragma unroll
            for (int r = 0; r < 16; ++r) min3f(rmin[r], dA0[r], dA1[r]);
        }
        {   // fold duo j+1 (dB) | mfma duo j+2 (bA->dA) | load duo j+3 (->bB)
            int tl = ((j + 3) & 15) * 2;
            bB0 = LDT(tl); bB1 = LDT(tl + 1);
            dA0 = mfma32(a, bA0); dA1 = mfma32(a, bA1);
            __builtin_amdgcn_sched_barrier(0);
            asm volatile("s_nop 7\n\ts_nop 7" : "+v"(dB0), "+v"(dB1));
            const int t = (j + 1) * 2;
            float c0 = tree16(dB0), c1 = tree16(dB1);
            c0 = fminf(c0, __shfl_xor(c0, 32, 64));
            c1 = fminf(c1, __shfl_xor(c1, 32, 64));
            ldscol[wv][t * 32 + colw]       = __float_as_uint(fmaxf(c0, 0.f));
            ldscol[wv][(t + 1) * 32 + colw] = __float_as_uint(fmaxf(c1, 0.f));
            #pragma unroll
            for (int r = 0; r < 16; ++r) min3f(rmin[r], dB0[r], dB1[r]);
        }
    }
#undef LDT

    // row side: min across the 32 cols (lane bits 0-4), then global atomicMin.
    #pragma unroll
    for (int r = 0; r < 16; ++r) {
        float v = rmin[r];
        v = fminf(v, __shfl_xor(v, 1, 64));
        v = fminf(v, __shfl_xor(v, 2, 64));
        v = fminf(v, __shfl_xor(v, 4, 64));
        v = fminf(v, __shfl_xor(v, 8, 64));
        v = fminf(v, __shfl_xor(v, 16, 64));
        if (colw == 0) {
            int rowg = mt * 32 + (r & 3) + 8 * (r >> 2) + 4 * laneHi;
            atomicMin(&rowmins[(size_t)n * NPTS + rowg],
                      __float_as_uint(fmaxf(v, 0.f)));
        }
    }

    // col side: merge 4 wave slices, one global atomicMin per column slot.
    __syncthreads();
    unsigned int* cbase = colmins + (size_t)n * NPTS + jc * (NT_PER * TPTS);
    for (int s = threadIdx.x; s < NT_PER * TPTS; s += 256) {
        unsigned int k = umin2(umin2(ldscol[0][s], ldscol[1][s]),
                               umin2(ldscol[2][s], ldscol[3][s]));
        atomicMin(&cbase[s], k);
    }
}

// out[n] = mean_i min_a2b + mean_j min_b2a  (P1 == P2 so one divide).
__global__ __launch_bounds__(1024) void chamfer_out(
    const unsigned int* __restrict__ mins, float* __restrict__ out)
{
    int n = blockIdx.x;
    float acc = 0.0f;
    for (int i = threadIdx.x; i < NPTS; i += 1024) {
        acc += __uint_as_float(mins[(0 * NBATCH + n) * NPTS + i]);
        acc += __uint_as_float(mins[(1 * NBATCH + n) * NPTS + i]);
    }
    for (int off = 32; off > 0; off >>= 1) acc += __shfl_down(acc, off, 64);
    __shared__ float sm[16];
    int wv = threadIdx.x >> 6, ln = threadIdx.x & 63;
    if (ln == 0) sm[wv] = acc;
    __syncthreads();
    if (threadIdx.x == 0) {
        float tot = 0.0f;
        #pragma unroll
        for (int w = 0; w < 16; ++w) tot += sm[w];
        out[n] = tot / (float)NPTS;
    }
}

extern "C" void kernel_launch(void* const* d_in, const int* in_sizes, int n_in,
                              void* d_out, int out_size, void* d_ws, size_t ws_size,
                              hipStream_t stream)
{
    const float* c1 = (const float*)d_in[0];
    const float* c2 = (const float*)d_in[1];
    float* out = (float*)d_out;

    char* ws = (char*)d_ws;
    // mins at base: 256 KiB. apan 1 MiB, bpan 1 MiB. Total 2.25 MiB.
    unsigned int*   mins = (unsigned int*)ws;
    unsigned short* apan = (unsigned short*)(ws + (size_t)(2 * NBATCH * NPTS) * 4);
    unsigned short* bpan = apan + (size_t)NBATCH * NTILES * 512;

    unsigned int* rowmins = mins;                          // cloud1 -> cloud2
    unsigned int* colmins = mins + (size_t)NBATCH * NPTS;  // cloud2 -> cloud1

    pack_panels<<<(1 << 17) / 256, 256, 0, stream>>>(c1, c2, apan, bpan, mins);
    chamfer_mm<<<NBATCH * TG * JCH, 256, 0, stream>>>(apan, bpan, rowmins, colmins);
    chamfer_out<<<NBATCH, 1024, 0, stream>>>(mins, out);
}

// Round 12
// 61.954 us; speedup vs baseline: 1.8995x; 1.0364x over previous
//
#include <hip/hip_runtime.h>

#define NBATCH 2
#define NPTS   16384
#define TPTS   32                      // points per MFMA tile (32x32x16)
#define NTILES (NPTS / TPTS)           // 512
#define JCH    16                      // col-chunks per batch: 1024 cols each
#define NT_PER (NTILES / JCH)          // 32 col-tiles per chunk
#define TG     (NTILES / 4)            // 128 row-groups (block = 4 waves = 128 rows)

typedef float f32x16 __attribute__((ext_vector_type(16)));
typedef short s16x8  __attribute__((ext_vector_type(8)));

__device__ __forceinline__ unsigned short f2bf(float f) {   // RTNE, finite inputs
    unsigned u = __float_as_uint(f);
    u += 0x7FFF + ((u >> 16) & 1);
    return (unsigned short)(u >> 16);
}
__device__ __forceinline__ float bf2f(unsigned short h) {
    return __uint_as_float((unsigned)h << 16);
}
__device__ __forceinline__ unsigned umin2(unsigned a, unsigned b) { return a < b ? a : b; }

// Inline-asm MFMA: VGPR destination (no ACC-class accvgpr_read tax),
// literal-0 C (no tied-C copy). Early-clobber dst so it can't alias a/b.
__device__ __forceinline__ f32x16 mfma32(s16x8 a, s16x8 b) {
    f32x16 d;
    asm volatile("v_mfma_f32_32x32x16_bf16 %0, %1, %2, 0"
                 : "=&v"(d) : "v"(a), "v"(b));
    return d;
}
__device__ __forceinline__ void min3f(float& acc, float x, float y) {
    asm("v_min3_f32 %0, %1, %2, %3" : "=v"(acc) : "v"(acc), "v"(x), "v"(y));
}
__device__ __forceinline__ float tree16(const f32x16& d) {  // min over 16 regs, 8 instrs
    float c;
    asm("v_min3_f32 %0, %1, %2, %3" : "=v"(c) : "v"(d[0]), "v"(d[1]), "v"(d[2]));
    min3f(c, d[3],  d[4]);  min3f(c, d[5],  d[6]);
    min3f(c, d[7],  d[8]);  min3f(c, d[9],  d[10]);
    min3f(c, d[11], d[12]); min3f(c, d[13], d[14]);
    return fminf(c, d[15]);
}

// K=16 panels, ONE matrix: rows = cloud1 (A-side), cols = cloud2 (B-side).
// A slots: [ah(3) | al(3) | ah(3) | 1 1 | sqa_h sqa_l | 0 0 0]
// B slots: [-2bh(3)| -2bh(3)| -2bl(3)| sqb_h sqb_l | 1 1 | 0 0 0]
// dot = sqa + sqb - 2(ah+al)·bh - 2ah·bl = d^2 + eps, |eps| <~ 1.3e-4 worst.
// Also initializes the mins arrays (fused memset).
__global__ __launch_bounds__(256) void pack_panels(
    const float* __restrict__ c1, const float* __restrict__ c2,
    unsigned short* __restrict__ apan, unsigned short* __restrict__ bpan,
    unsigned int* __restrict__ mins)
{
    int tid = blockIdx.x * 256 + threadIdx.x;   // 2^17 threads
    if (tid < 2 * NBATCH * NPTS) mins[tid] = 0x7F7F7F7Fu;   // fused init

    int lane   = tid & 63;
    int tile   = (tid >> 6) & (NTILES - 1);
    int n      = (tid >> 15) & 1;
    int whichB = (tid >> 16) & 1;

    const float* src = whichB ? c2 : c1;

    int p = tile * TPTS + (lane & 31);
    const float* q = src + ((size_t)n * NPTS + p) * 3;
    float x = q[0], y = q[1], z = q[2];

    unsigned short xh = f2bf(x), yh = f2bf(y), zh = f2bf(z);
    unsigned short xl = f2bf(x - bf2f(xh)), yl = f2bf(y - bf2f(yh)), zl = f2bf(z - bf2f(zh));
    float sq = x * x + y * y + z * z;
    unsigned short sh = f2bf(sq);
    unsigned short sl = f2bf(sq - bf2f(sh));
    const unsigned short one = 0x3F80;

    unsigned short slots[16];
    if (!whichB) {
        slots[0]=xh;  slots[1]=yh;  slots[2]=zh;
        slots[3]=xl;  slots[4]=yl;  slots[5]=zl;
        slots[6]=xh;  slots[7]=yh;  slots[8]=zh;
        slots[9]=one; slots[10]=one;
        slots[11]=sh; slots[12]=sl;
        slots[13]=0;  slots[14]=0;  slots[15]=0;
    } else {
        unsigned short mxh=f2bf(-2.f*bf2f(xh)), myh=f2bf(-2.f*bf2f(yh)), mzh=f2bf(-2.f*bf2f(zh));
        unsigned short mxl=f2bf(-2.f*bf2f(xl)), myl=f2bf(-2.f*bf2f(yl)), mzl=f2bf(-2.f*bf2f(zl));
        slots[0]=mxh; slots[1]=myh; slots[2]=mzh;
        slots[3]=mxh; slots[4]=myh; slots[5]=mzh;
        slots[6]=mxl; slots[7]=myl; slots[8]=mzl;
        slots[9]=sh;  slots[10]=sl;
        slots[11]=one; slots[12]=one;
        slots[13]=0;  slots[14]=0;  slots[15]=0;
    }

    int j0 = (lane >> 5) * 8;
    uint4 w;
    w.x = (unsigned)slots[j0+0] | ((unsigned)slots[j0+1] << 16);
    w.y = (unsigned)slots[j0+2] | ((unsigned)slots[j0+3] << 16);
    w.z = (unsigned)slots[j0+4] | ((unsigned)slots[j0+5] << 16);
    w.w = (unsigned)slots[j0+6] | ((unsigned)slots[j0+7] << 16);
    unsigned short* pan = whichB ? bpan : apan;
    uint4* dst = (uint4*)pan + ((size_t)(n * NTILES + tile) * 64 + lane);
    *dst = w;
}

// One pass over the d^2 matrix -> BOTH reductions, raw-value min3 folds.
// 3-stage pipeline: load duo t+2 | MFMA duo t+1 | fold duo t. Hazard guard:
// s_nop pair with INPUT-ONLY ties (no "+v" -> no register-copy tax), pinned
// by sched_barrier(0) on both sides (rule #18). Col partials: per-wave LDS
// slices, plain stores (lanes l and l+32 store the same folded value to the
// same address - benign), merged after syncthreads.
// D layout (R7/R9 HW-verified): col=lane&31, row=(r&3)+8*(r>>2)+4*(lane>>5).
__global__ __launch_bounds__(256, 4) void chamfer_mm(
    const unsigned short* __restrict__ apan, const unsigned short* __restrict__ bpan,
    unsigned int* __restrict__ rowmins, unsigned int* __restrict__ colmins)
{
    __shared__ unsigned int ldscol[4][NT_PER * TPTS];   // 16 KiB

    int bid = blockIdx.x;
    const int jc = bid & (JCH - 1); bid >>= 4;
    const int tg = bid & (TG - 1);  bid >>= 7;
    const int n  = bid;

    const int lane   = threadIdx.x & 63;
    const int wv     = threadIdx.x >> 6;
    const int colw   = lane & 31;
    const int laneHi = lane >> 5;
    const int mt     = tg * 4 + wv;      // this wave's row-tile (32 rows)

    const s16x8 a = *(const s16x8*)(
        apan + ((size_t)(n * NTILES + mt) * 64 + lane) * 8);
    const unsigned short* B =
        bpan + ((size_t)(n * NTILES + jc * NT_PER) * 64 + lane) * 8;

#define LDT(t) (*(const s16x8*)(B + (size_t)(t) * 512))

    float rmin[16];
    #pragma unroll
    for (int r = 0; r < 16; ++r) rmin[r] = 3.0e38f;

    // prologue: duos 0,1 loaded; duo0 in flight
    s16x8 bA0 = LDT(0), bA1 = LDT(1);
    s16x8 bB0 = LDT(2), bB1 = LDT(3);
    f32x16 dA0 = mfma32(a, bA0), dA1 = mfma32(a, bA1);
    f32x16 dB0, dB1;

    #pragma unroll
    for (int j = 0; j < 16; j += 2) {
        {   // fold duo j (dA) | mfma duo j+1 (bB->dB) | load duo j+2 (->bA)
            const int tl = ((j + 2) & 15) * 2;
            bA0 = LDT(tl); bA1 = LDT(tl + 1);
            dB0 = mfma32(a, bB0); dB1 = mfma32(a, bB1);
            __builtin_amdgcn_sched_barrier(0);
            asm volatile("s_nop 7\n\ts_nop 7" :: "v"(dA0), "v"(dA1));
            __builtin_amdgcn_sched_barrier(0);
            const int t = j * 2;
            float c0 = tree16(dA0), c1 = tree16(dA1);
            c0 = fminf(c0, __shfl_xor(c0, 32, 64));
            c1 = fminf(c1, __shfl_xor(c1, 32, 64));
            ldscol[wv][t * 32 + colw]       = __float_as_uint(fmaxf(c0, 0.f));
            ldscol[wv][(t + 1) * 32 + colw] = __float_as_uint(fmaxf(c1, 0.f));
            #pragma unroll
            for (int r = 0; r < 16; ++r) min3f(rmin[r], dA0[r], dA1[r]);
        }
        {   // fold duo j+1 (dB) | mfma duo j+2 (bA->dA) | load duo j+3 (->bB)
            const int tl = ((j + 3) & 15) * 2;
            bB0 = LDT(tl); bB1 = LDT(tl + 1);
            dA0 = mfma32(a, bA0); dA1 = mfma32(a, bA1);
            __builtin_amdgcn_sched_barrier(0);
            asm volatile("s_nop 7\n\ts_nop 7" :: "v"(dB0), "v"(dB1));
            __builtin_amdgcn_sched_barrier(0);
            const int t = (j + 1) * 2;
            float c0 = tree16(dB0), c1 = tree16(dB1);
            c0 = fminf(c0, __shfl_xor(c0, 32, 64));
            c1 = fminf(c1, __shfl_xor(c1, 32, 64));
            ldscol[wv][t * 32 + colw]       = __float_as_uint(fmaxf(c0, 0.f));
            ldscol[wv][(t + 1) * 32 + colw] = __float_as_uint(fmaxf(c1, 0.f));
            #pragma unroll
            for (int r = 0; r < 16; ++r) min3f(rmin[r], dB0[r], dB1[r]);
        }
    }
#undef LDT

    // row side: min across the 32 cols (lane bits 0-4), then global atomicMin.
    #pragma unroll
    for (int r = 0; r < 16; ++r) {
        float v = rmin[r];
        v = fminf(v, __shfl_xor(v, 1, 64));
        v = fminf(v, __shfl_xor(v, 2, 64));
        v = fminf(v, __shfl_xor(v, 4, 64));
        v = fminf(v, __shfl_xor(v, 8, 64));
        v = fminf(v, __shfl_xor(v, 16, 64));
        if (colw == 0) {
            int rowg = mt * 32 + (r & 3) + 8 * (r >> 2) + 4 * laneHi;
            atomicMin(&rowmins[(size_t)n * NPTS + rowg],
                      __float_as_uint(fmaxf(v, 0.f)));
        }
    }

    // col side: merge 4 wave slices, one global atomicMin per column slot.
    __syncthreads();
    unsigned int* cbase = colmins + (size_t)n * NPTS + jc * (NT_PER * TPTS);
    #pragma unroll
    for (int u = 0; u < (NT_PER * TPTS) / 256; ++u) {
        int s = u * 256 + threadIdx.x;
        unsigned int k = umin2(umin2(ldscol[0][s], ldscol[1][s]),
                               umin2(ldscol[2][s], ldscol[3][s]));
        atomicMin(&cbase[s], k);
    }
}

// out[n] = mean_i min_a2b + mean_j min_b2a  (P1 == P2 so one divide).
__global__ __launch_bounds__(1024) void chamfer_out(
    const unsigned int* __restrict__ mins, float* __restrict__ out)
{
    int n = blockIdx.x;
    float acc = 0.0f;
    for (int i = threadIdx.x; i < NPTS; i += 1024) {
        acc += __uint_as_float(mins[(0 * NBATCH + n) * NPTS + i]);
        acc += __uint_as_float(mins[(1 * NBATCH + n) * NPTS + i]);
    }
    for (int off = 32; off > 0; off >>= 1) acc += __shfl_down(acc, off, 64);
    __shared__ float sm[16];
    int wv = threadIdx.x >> 6, ln = threadIdx.x & 63;
    if (ln == 0) sm[wv] = acc;
    __syncthreads();
    if (threadIdx.x == 0) {
        float tot = 0.0f;
        #pragma unroll
        for (int w = 0; w < 16; ++w) tot += sm[w];
        out[n] = tot / (float)NPTS;
    }
}

extern "C" void kernel_launch(void* const* d_in, const int* in_sizes, int n_in,
                              void* d_out, int out_size, void* d_ws, size_t ws_size,
                              hipStream_t stream)
{
    const float* c1 = (const float*)d_in[0];
    const float* c2 = (const float*)d_in[1];
    float* out = (float*)d_out;

    char* ws = (char*)d_ws;
    // mins at base: 256 KiB. apan 1 MiB, bpan 1 MiB. Total 2.25 MiB.
    unsigned int*   mins = (unsigned int*)ws;
    unsigned short* apan = (unsigned short*)(ws + (size_t)(2 * NBATCH * NPTS) * 4);
    unsigned short* bpan = apan + (size_t)NBATCH * NTILES * 512;

    unsigned int* rowmins = mins;                          // cloud1 -> cloud2
    unsigned int* colmins = mins + (size_t)NBATCH * NPTS;  // cloud2 -> cloud1

    pack_panels<<<(1 << 17) / 256, 256, 0, stream>>>(c1, c2, apan, bpan, mins);
    chamfer_mm<<<NBATCH * TG * JCH, 256, 0, stream>>>(apan, bpan, rowmins, colmins);
    chamfer_out<<<NBATCH, 1024, 0, stream>>>(mins, out);
}

// Round 13
// 61.262 us; speedup vs baseline: 1.9210x; 1.0113x over previous
//
#include <hip/hip_runtime.h>

#define NBATCH 2
#define NPTS   16384
#define TPTS   32                      // points per MFMA tile (32x32x16)
#define NTILES (NPTS / TPTS)           // 512
#define JCH    16                      // col-chunks per batch: 1024 cols each
#define NT_PER (NTILES / JCH)          // 32 col-tiles per chunk
#define TG     (NTILES / 4)            // 128 row-groups (block = 4 waves = 128 rows)

typedef float f32x16 __attribute__((ext_vector_type(16)));
typedef short s16x8  __attribute__((ext_vector_type(8)));

__device__ __forceinline__ unsigned short f2bf(float f) {   // RTNE, finite inputs
    unsigned u = __float_as_uint(f);
    u += 0x7FFF + ((u >> 16) & 1);
    return (unsigned short)(u >> 16);
}
__device__ __forceinline__ float bf2f(unsigned short h) {
    return __uint_as_float((unsigned)h << 16);
}
__device__ __forceinline__ unsigned umin2(unsigned a, unsigned b) { return a < b ? a : b; }

// Inline-asm MFMA: VGPR destination (no ACC-class tax), literal-0 C.
__device__ __forceinline__ f32x16 mfma32(s16x8 a, s16x8 b) {
    f32x16 d;
    asm volatile("v_mfma_f32_32x32x16_bf16 %0, %1, %2, 0"
                 : "=&v"(d) : "v"(a), "v"(b));
    return d;
}
__device__ __forceinline__ float min3v(float x, float y, float z) {
    float r;
    asm("v_min3_f32 %0, %1, %2, %3" : "=v"(r) : "v"(x), "v"(y), "v"(z));
    return r;
}
__device__ __forceinline__ void min2v(float& acc, float x) {
    asm("v_min_f32 %0, %1, %2" : "=v"(acc) : "v"(acc), "v"(x));
}

// K=16 panels, ONE matrix: rows = cloud1 (A-side), cols = cloud2 (B-side).
// A slots: [ah(3) | al(3) | ah(3) | 1 1 | sqa_h sqa_l | 0 0 0]
// B slots: [-2bh(3)| -2bh(3)| -2bl(3)| sqb_h sqb_l | 1 1 | 0 0 0]
// dot = sqa + sqb - 2(ah+al)·bh - 2ah·bl = d^2 + eps, |eps| <~ 1.3e-4 worst.
// Also initializes the mins arrays (fused memset).
__global__ __launch_bounds__(256) void pack_panels(
    const float* __restrict__ c1, const float* __restrict__ c2,
    unsigned short* __restrict__ apan, unsigned short* __restrict__ bpan,
    unsigned int* __restrict__ mins)
{
    int tid = blockIdx.x * 256 + threadIdx.x;   // 2^17 threads
    if (tid < 2 * NBATCH * NPTS) mins[tid] = 0x7F7F7F7Fu;   // fused init

    int lane   = tid & 63;
    int tile   = (tid >> 6) & (NTILES - 1);
    int n      = (tid >> 15) & 1;
    int whichB = (tid >> 16) & 1;

    const float* src = whichB ? c2 : c1;

    int p = tile * TPTS + (lane & 31);
    const float* q = src + ((size_t)n * NPTS + p) * 3;
    float x = q[0], y = q[1], z = q[2];

    unsigned short xh = f2bf(x), yh = f2bf(y), zh = f2bf(z);
    unsigned short xl = f2bf(x - bf2f(xh)), yl = f2bf(y - bf2f(yh)), zl = f2bf(z - bf2f(zh));
    float sq = x * x + y * y + z * z;
    unsigned short sh = f2bf(sq);
    unsigned short sl = f2bf(sq - bf2f(sh));
    const unsigned short one = 0x3F80;

    unsigned short slots[16];
    if (!whichB) {
        slots[0]=xh;  slots[1]=yh;  slots[2]=zh;
        slots[3]=xl;  slots[4]=yl;  slots[5]=zl;
        slots[6]=xh;  slots[7]=yh;  slots[8]=zh;
        slots[9]=one; slots[10]=one;
        slots[11]=sh; slots[12]=sl;
        slots[13]=0;  slots[14]=0;  slots[15]=0;
    } else {
        unsigned short mxh=f2bf(-2.f*bf2f(xh)), myh=f2bf(-2.f*bf2f(yh)), mzh=f2bf(-2.f*bf2f(zh));
        unsigned short mxl=f2bf(-2.f*bf2f(xl)), myl=f2bf(-2.f*bf2f(yl)), mzl=f2bf(-2.f*bf2f(zl));
        slots[0]=mxh; slots[1]=myh; slots[2]=mzh;
        slots[3]=mxh; slots[4]=myh; slots[5]=mzh;
        slots[6]=mxl; slots[7]=myl; slots[8]=mzl;
        slots[9]=sh;  slots[10]=sl;
        slots[11]=one; slots[12]=one;
        slots[13]=0;  slots[14]=0;  slots[15]=0;
    }

    int j0 = (lane >> 5) * 8;
    uint4 w;
    w.x = (unsigned)slots[j0+0] | ((unsigned)slots[j0+1] << 16);
    w.y = (unsigned)slots[j0+2] | ((unsigned)slots[j0+3] << 16);
    w.z = (unsigned)slots[j0+4] | ((unsigned)slots[j0+5] << 16);
    w.w = (unsigned)slots[j0+6] | ((unsigned)slots[j0+7] << 16);
    unsigned short* pan = whichB ? bpan : apan;
    uint4* dst = (uint4*)pan + ((size_t)(n * NTILES + tile) * 64 + lane);
    *dst = w;
}

// Single-tile pipeline, minimal VGPR (<=64 -> 8 waves/SIMD budget), prefetch
// distance 3 tiles (~3 phases ~= L2 latency). No shfl in the hot loop: col
// partials go to per-(wave,laneHi) LDS slices with plain ds_write at
// compile-time offsets; merged in epilogue. Hazard guard (rule #18):
// sched_barrier + s_nop pair + sched_barrier between asm MFMA and its reads.
// D layout (R7/R9 HW-verified): col=lane&31, row=(r&3)+8*(r>>2)+4*(lane>>5).
__global__ __launch_bounds__(256, 8) void chamfer_mm(
    const unsigned short* __restrict__ apan, const unsigned short* __restrict__ bpan,
    unsigned int* __restrict__ rowmins, unsigned int* __restrict__ colmins)
{
    __shared__ unsigned int ldscol[8][NT_PER * TPTS];   // [wv*2+laneHi][slot] 32 KiB

    int bid = blockIdx.x;
    const int jc = bid & (JCH - 1); bid >>= 4;
    const int tg = bid & (TG - 1);  bid >>= 7;
    const int n  = bid;

    const int lane   = threadIdx.x & 63;
    const int wv     = threadIdx.x >> 6;
    const int colw   = lane & 31;
    const int laneHi = lane >> 5;
    const int mt     = tg * 4 + wv;      // this wave's row-tile (32 rows)

    const s16x8 a = *(const s16x8*)(
        apan + ((size_t)(n * NTILES + mt) * 64 + lane) * 8);
    const unsigned short* B =
        bpan + ((size_t)(n * NTILES + jc * NT_PER) * 64 + lane) * 8;

    unsigned int* lcol = &ldscol[wv * 2 + laneHi][colw];

#define LDT(t) (*(const s16x8*)(B + (size_t)(t) * 512))

    float rmin[16];
    #pragma unroll
    for (int r = 0; r < 16; ++r) rmin[r] = 3.0e38f;

    // b-ring: 4 tiles in flight, prefetch distance 3
    s16x8 b0 = LDT(0), b1 = LDT(1), b2 = LDT(2);

    #pragma unroll
    for (int t = 0; t < NT_PER; ++t) {
        s16x8 bn = LDT((t + 3) & (NT_PER - 1));   // wraps at tail: harmless L2 hits
        f32x16 d = mfma32(a, b0);
        __builtin_amdgcn_sched_barrier(0);
        asm volatile("s_nop 7\n\ts_nop 7" :: "v"(d));
        __builtin_amdgcn_sched_barrier(0);
        // col fold: balanced min3 tree (8 instrs, depth 3)
        float q0 = min3v(d[0],  d[1],  d[2]);
        float q1 = min3v(d[3],  d[4],  d[5]);
        float q2 = min3v(d[6],  d[7],  d[8]);
        float q3 = min3v(d[9],  d[10], d[11]);
        float q4 = min3v(d[12], d[13], d[14]);
        float u0 = min3v(q0, q1, q2);
        float u1 = min3v(q3, q4, d[15]);
        lcol[t * 32] = __float_as_uint(fmaxf(fminf(u0, u1), 0.f));
        // row folds: 16 independent v_min_f32
        #pragma unroll
        for (int r = 0; r < 16; ++r) min2v(rmin[r], d[r]);
        // rotate ring (copies coalesce under full unroll)
        b0 = b1; b1 = b2; b2 = bn;
    }
#undef LDT

    // row side: butterfly min across the 32 cols (lane bits 0-4; 16 regs give
    // the ILP to hide ds_swizzle latency), then global atomicMin.
    #pragma unroll
    for (int r = 0; r < 16; ++r) {
        float v = rmin[r];
        v = fminf(v, __shfl_xor(v, 1, 64));
        v = fminf(v, __shfl_xor(v, 2, 64));
        v = fminf(v, __shfl_xor(v, 4, 64));
        v = fminf(v, __shfl_xor(v, 8, 64));
        v = fminf(v, __shfl_xor(v, 16, 64));
        if (colw == 0) {
            int rowg = mt * 32 + (r & 3) + 8 * (r >> 2) + 4 * laneHi;
            atomicMin(&rowmins[(size_t)n * NPTS + rowg],
                      __float_as_uint(fmaxf(v, 0.f)));
        }
    }

    // col side: merge 8 slices, one global atomicMin per column slot.
    __syncthreads();
    unsigned int* cbase = colmins + (size_t)n * NPTS + jc * (NT_PER * TPTS);
    #pragma unroll
    for (int u = 0; u < (NT_PER * TPTS) / 256; ++u) {
        int s = u * 256 + threadIdx.x;
        unsigned int k = ldscol[0][s];
        k = umin2(k, ldscol[1][s]);
        k = umin2(k, ldscol[2][s]);
        k = umin2(k, ldscol[3][s]);
        k = umin2(k, ldscol[4][s]);
        k = umin2(k, ldscol[5][s]);
        k = umin2(k, ldscol[6][s]);
        k = umin2(k, ldscol[7][s]);
        atomicMin(&cbase[s], k);
    }
}

// out[n] = mean_i min_a2b + mean_j min_b2a  (P1 == P2 so one divide).
__global__ __launch_bounds__(1024) void chamfer_out(
    const unsigned int* __restrict__ mins, float* __restrict__ out)
{
    int n = blockIdx.x;
    float acc = 0.0f;
    for (int i = threadIdx.x; i < NPTS; i += 1024) {
        acc += __uint_as_float(mins[(0 * NBATCH + n) * NPTS + i]);
        acc += __uint_as_float(mins[(1 * NBATCH + n) * NPTS + i]);
    }
    for (int off = 32; off > 0; off >>= 1) acc += __shfl_down(acc, off, 64);
    __shared__ float sm[16];
    int wv = threadIdx.x >> 6, ln = threadIdx.x & 63;
    if (ln == 0) sm[wv] = acc;
    __syncthreads();
    if (threadIdx.x == 0) {
        float tot = 0.0f;
        #pragma unroll
        for (int w = 0; w < 16; ++w) tot += sm[w];
        out[n] = tot / (float)NPTS;
    }
}

extern "C" void kernel_launch(void* const* d_in, const int* in_sizes, int n_in,
                              void* d_out, int out_size, void* d_ws, size_t ws_size,
                              hipStream_t stream)
{
    const float* c1 = (const float*)d_in[0];
    const float* c2 = (const float*)d_in[1];
    float* out = (float*)d_out;

    char* ws = (char*)d_ws;
    // mins at base: 256 KiB. apan 1 MiB, bpan 1 MiB. Total 2.25 MiB.
    unsigned int*   mins = (unsigned int*)ws;
    unsigned short* apan = (unsigned short*)(ws + (size_t)(2 * NBATCH * NPTS) * 4);
    unsigned short* bpan = apan + (size_t)NBATCH * NTILES * 512;

    unsigned int* rowmins = mins;                          // cloud1 -> cloud2
    unsigned int* colmins = mins + (size_t)NBATCH * NPTS;  // cloud2 -> cloud1

    pack_panels<<<(1 << 17) / 256, 256, 0, stream>>>(c1, c2, apan, bpan, mins);
    chamfer_mm<<<NBATCH * TG * JCH, 256, 0, stream>>>(apan, bpan, rowmins, colmins);
    chamfer_out<<<NBATCH, 1024, 0, stream>>>(mins, out);
}